// Round 3
// baseline (223.635 us; speedup 1.0000x reference)
//
#include <hip/hip_runtime.h>
#include <hip/hip_bf16.h>

#define N_NODES 50000
#define KNB 16
#define FDIM 128
#define HDIM 128
#define ALPHA 0.3f
#define BN_EPS 1e-3f

typedef __bf16 v8bf __attribute__((ext_vector_type(8)));
typedef float v4f __attribute__((ext_vector_type(4)));

__device__ __forceinline__ float bf2f(unsigned int u16bits) {
    union { float f; unsigned int i; } x;
    x.i = u16bits << 16;
    return x.f;
}

__device__ __forceinline__ unsigned short f2bf(float f) {
    union { float f; unsigned int u; } x;
    x.f = f;
    unsigned int r = x.u + 0x7fffu + ((x.u >> 16) & 1u);  // RNE
    return (unsigned short)(r >> 16);
}

__device__ __forceinline__ float lrelu(float x) { return x > 0.f ? x : ALPHA * x; }

// load 8 consecutive f32 and convert to a bf16 MFMA fragment (RNE)
__device__ __forceinline__ v8bf load8f(const float* p) {
    float4 a = *(const float4*)p;
    float4 b = *(const float4*)(p + 4);
    union { v8bf v; unsigned short u[8]; } r;
    r.u[0] = f2bf(a.x); r.u[1] = f2bf(a.y); r.u[2] = f2bf(a.z); r.u[3] = f2bf(a.w);
    r.u[4] = f2bf(b.x); r.u[5] = f2bf(b.y); r.u[6] = f2bf(b.z); r.u[7] = f2bf(b.w);
    return r.v;
}

// ---------------------------------------------------------------------------
// Kernel A: Q = lrelu(E@Wq+bq) [f32 -> d_out], K,V likewise [bf16 -> ws].
// 128 rows/block, 4 waves, 16x16x32 bf16 MFMA, f32 inputs converted on load.
// ---------------------------------------------------------------------------
__global__ __launch_bounds__(256) void qkv_kernel(
    const float* __restrict__ E,
    const float* __restrict__ Wq, const float* __restrict__ bq,
    const float* __restrict__ Wk, const float* __restrict__ bk,
    const float* __restrict__ Wv, const float* __restrict__ bv,
    float* __restrict__ Qo, unsigned short* __restrict__ Ko,
    unsigned short* __restrict__ Vo)
{
    __shared__ unsigned short sW[128 * 136];  // W^T [n][k] bf16, stride 136 (272B)

    const int tid  = threadIdx.x;
    const int wave = tid >> 6;
    const int lane = tid & 63;
    const int quad = lane >> 4;
    const int j    = lane & 15;
    const int row0 = blockIdx.x * 128 + wave * 32;

    const float* Ws[3] = {Wq, Wk, Wv};
    const float* bs[3] = {bq, bk, bv};

    const int ar0 = min(row0 + j,      N_NODES - 1);
    const int ar1 = min(row0 + 16 + j, N_NODES - 1);

    for (int w = 0; w < 3; ++w) {
        const float* W = Ws[w];
        for (int idx = tid; idx < 128 * 128; idx += 256) {
            int k = idx >> 7, n = idx & 127;     // W is [k][n] row-major
            sW[n * 136 + k] = f2bf(W[idx]);
        }
        __syncthreads();

        v4f acc[2][8];
#pragma unroll
        for (int rb = 0; rb < 2; ++rb)
#pragma unroll
            for (int c = 0; c < 8; ++c) acc[rb][c] = (v4f){0.f, 0.f, 0.f, 0.f};

#pragma unroll
        for (int ks = 0; ks < 4; ++ks) {
            const int k0 = ks * 32 + quad * 8;
            v8bf a0 = load8f(E + (size_t)ar0 * FDIM + k0);
            v8bf a1 = load8f(E + (size_t)ar1 * FDIM + k0);
            v8bf b[8];
#pragma unroll
            for (int c = 0; c < 8; ++c)
                b[c] = *(const v8bf*)(&sW[(c * 16 + j) * 136 + k0]);
#pragma unroll
            for (int c = 0; c < 8; ++c) {
                acc[0][c] = __builtin_amdgcn_mfma_f32_16x16x32_bf16(a0, b[c], acc[0][c], 0, 0, 0);
                acc[1][c] = __builtin_amdgcn_mfma_f32_16x16x32_bf16(a1, b[c], acc[1][c], 0, 0, 0);
            }
        }

        const float* bias = bs[w];
#pragma unroll
        for (int c = 0; c < 8; ++c) {
            const int col = c * 16 + j;
            const float bv_ = bias[col];
#pragma unroll
            for (int rb = 0; rb < 2; ++rb) {
#pragma unroll
                for (int i = 0; i < 4; ++i) {
                    const int r = row0 + rb * 16 + quad * 4 + i;
                    if (r < N_NODES) {
                        const float x = lrelu(acc[rb][c][i] + bv_);
                        if (w == 0)      Qo[(size_t)r * HDIM + col] = x;
                        else if (w == 1) Ko[(size_t)r * HDIM + col] = f2bf(x);
                        else             Vo[(size_t)r * HDIM + col] = f2bf(x);
                    }
                }
            }
        }
        __syncthreads();
    }
}

// ---------------------------------------------------------------------------
// Kernel B: per-node 16-neighbor attention pool. One wave per node.
// Reads q (f32) from QP[node], overwrites the same row with pooled (f32).
// ---------------------------------------------------------------------------
__global__ __launch_bounds__(256) void attn_kernel(
    float* __restrict__ QP, const unsigned short* __restrict__ K,
    const unsigned short* __restrict__ V, const int* __restrict__ nbr,
    int n_nodes)
{
    const int tid  = threadIdx.x;
    const int wave = tid >> 6;
    const int lane = tid & 63;
    const int node = blockIdx.x * 4 + wave;
    if (node >= n_nodes) return;

    const float2 qp = ((const float2*)(QP + (size_t)node * HDIM))[lane];

    int idxs[KNB];
    const int* nb = nbr + node * KNB;
#pragma unroll
    for (int t = 0; t < KNB; ++t) {
        int id = nb[t];
        idxs[t] = ((unsigned)id < (unsigned)n_nodes) ? id : 0;  // defensive clamp
    }

    float sc[KNB];
#pragma unroll
    for (int t = 0; t < KNB; ++t) {
        const unsigned int kp = ((const unsigned int*)(K + (size_t)idxs[t] * HDIM))[lane];
        float p = qp.x * bf2f(kp & 0xffffu) + qp.y * bf2f(kp >> 16);
#pragma unroll
        for (int off = 32; off >= 1; off >>= 1) p += __shfl_xor(p, off, 64);
        sc[t] = p;
    }

    float m = sc[0];
#pragma unroll
    for (int t = 1; t < KNB; ++t) m = fmaxf(m, sc[t]);
    float s = 0.f;
#pragma unroll
    for (int t = 0; t < KNB; ++t) { sc[t] = __expf(sc[t] - m); s += sc[t]; }
    const float inv = 1.f / s;

    float p0 = 0.f, p1 = 0.f;
#pragma unroll
    for (int t = 0; t < KNB; ++t) {
        const unsigned int vp = ((const unsigned int*)(V + (size_t)idxs[t] * HDIM))[lane];
        const float a = sc[t] * inv;
        p0 += a * bf2f(vp & 0xffffu);
        p1 += a * bf2f(vp >> 16);
    }

    ((float2*)(QP + (size_t)node * HDIM))[lane] = make_float2(p0, p1);
}

// ---------------------------------------------------------------------------
// Kernel C: out = BN(rownorm(lrelu(concat(E,pooled)@W1 + b1)))  [f32 out]
// pooled lives in d_out; result overwrites d_out. The barrier at the end of
// the half=1 stage loop orders all pooled reads before any epilogue write
// within a block; blocks own disjoint row ranges (only block 390 clamps, and
// only onto its own rows) — no cross-block hazard.
// ---------------------------------------------------------------------------
__global__ __launch_bounds__(256) void out_kernel(
    const float* __restrict__ E, const float* __restrict__ W1,
    const float* __restrict__ b1,
    const float* __restrict__ gamma, const float* __restrict__ beta,
    const float* __restrict__ mmean, const float* __restrict__ mvar,
    float* __restrict__ OutP)   // pooled (in) + out (result)
{
    __shared__ unsigned short sW[128 * 136];

    const int tid  = threadIdx.x;
    const int wave = tid >> 6;
    const int lane = tid & 63;
    const int quad = lane >> 4;
    const int j    = lane & 15;
    const int row0 = blockIdx.x * 128 + wave * 32;

    const int ar0 = min(row0 + j,      N_NODES - 1);
    const int ar1 = min(row0 + 16 + j, N_NODES - 1);

    v4f acc[2][8];
#pragma unroll
    for (int rb = 0; rb < 2; ++rb)
#pragma unroll
        for (int c = 0; c < 8; ++c) acc[rb][c] = (v4f){0.f, 0.f, 0.f, 0.f};

    for (int half = 0; half < 2; ++half) {
        // stage W1^T bf16 rows k in [half*128, half*128+128); W1 is [256][128]
        for (int idx = tid; idx < 128 * 128; idx += 256) {
            int k = idx >> 7, n = idx & 127;
            sW[n * 136 + k] = f2bf(W1[idx + half * 16384]);
        }
        __syncthreads();

        const float* Abase = (half == 0) ? E : (const float*)OutP;
#pragma unroll
        for (int ks = 0; ks < 4; ++ks) {
            const int k0 = ks * 32 + quad * 8;
            v8bf a0 = load8f(Abase + (size_t)ar0 * 128 + k0);
            v8bf a1 = load8f(Abase + (size_t)ar1 * 128 + k0);
            v8bf b[8];
#pragma unroll
            for (int c = 0; c < 8; ++c)
                b[c] = *(const v8bf*)(&sW[(c * 16 + j) * 136 + k0]);
#pragma unroll
            for (int c = 0; c < 8; ++c) {
                acc[0][c] = __builtin_amdgcn_mfma_f32_16x16x32_bf16(a0, b[c], acc[0][c], 0, 0, 0);
                acc[1][c] = __builtin_amdgcn_mfma_f32_16x16x32_bf16(a1, b[c], acc[1][c], 0, 0, 0);
            }
        }
        __syncthreads();   // orders pooled reads before epilogue writes
    }

    // Per-column epilogue constants: BN folded to h*s + t.
    float scale_[8], shift_[8], bias_[8];
#pragma unroll
    for (int c = 0; c < 8; ++c) {
        const int col = c * 16 + j;
        const float g  = gamma[col];
        const float be = beta[col];
        const float mu = mmean[col];
        const float vv = mvar[col];
        const float s = g * rsqrtf(vv + BN_EPS);
        scale_[c] = s;
        shift_[c] = be - mu * s;
        bias_[c]  = b1[col];
    }

    // h = lrelu(acc + b1) in place
#pragma unroll
    for (int rb = 0; rb < 2; ++rb)
#pragma unroll
        for (int c = 0; c < 8; ++c)
#pragma unroll
            for (int i = 0; i < 4; ++i)
                acc[rb][c][i] = lrelu(acc[rb][c][i] + bias_[c]);

    // Row L2-norm: a row's 128 cols live in this quad's 16 lanes x 8 col-frags.
#pragma unroll
    for (int rb = 0; rb < 2; ++rb) {
#pragma unroll
        for (int i = 0; i < 4; ++i) {
            float ss = 0.f;
#pragma unroll
            for (int c = 0; c < 8; ++c) ss += acc[rb][c][i] * acc[rb][c][i];
            ss += __shfl_xor(ss, 1, 64);
            ss += __shfl_xor(ss, 2, 64);
            ss += __shfl_xor(ss, 4, 64);
            ss += __shfl_xor(ss, 8, 64);
            const float invn = 1.f / (sqrtf(ss) + 1e-6f);
            const int r = row0 + rb * 16 + quad * 4 + i;
            if (r < N_NODES) {
#pragma unroll
                for (int c = 0; c < 8; ++c) {
                    const float o = acc[rb][c][i] * invn * scale_[c] + shift_[c];
                    OutP[(size_t)r * HDIM + c * 16 + j] = o;
                }
            }
        }
    }
}

extern "C" void kernel_launch(void* const* d_in, const int* in_sizes, int n_in,
                              void* d_out, int out_size, void* d_ws, size_t ws_size,
                              hipStream_t stream)
{
    const float* E     = (const float*)d_in[0];
    const int*   nbr   = (const int*)d_in[2];
    const float* Wq    = (const float*)d_in[3];
    const float* bq    = (const float*)d_in[4];
    const float* Wk    = (const float*)d_in[5];
    const float* bk    = (const float*)d_in[6];
    const float* Wv    = (const float*)d_in[7];
    const float* bv    = (const float*)d_in[8];
    const float* W1    = (const float*)d_in[9];
    const float* b1    = (const float*)d_in[10];
    const float* gam   = (const float*)d_in[11];
    const float* bet   = (const float*)d_in[12];
    const float* mmean = (const float*)d_in[13];
    const float* mvar  = (const float*)d_in[14];

    // ws: K bf16 (12.8 MB) + V bf16 (12.8 MB) = 25.6 MB.
    // Q (f32) and pooled (f32) share d_out (25.6 MB): written by qkv,
    // transformed in-place by attn, consumed+overwritten by out_kernel.
    unsigned short* Ko = (unsigned short*)d_ws;
    unsigned short* Vo = Ko + (size_t)N_NODES * HDIM;
    float* QP = (float*)d_out;

    const int gridA = (N_NODES + 127) / 128;  // 391
    qkv_kernel<<<gridA, 256, 0, stream>>>(E, Wq, bq, Wk, bk, Wv, bv, QP, Ko, Vo);
    attn_kernel<<<(N_NODES + 3) / 4, 256, 0, stream>>>(QP, Ko, Vo, nbr, N_NODES);
    out_kernel<<<gridA, 256, 0, stream>>>(E, W1, b1, gam, bet, mmean, mvar, QP);
}